// Round 6
// baseline (3509.492 us; speedup 1.0000x reference)
//
#include <hip/hip_runtime.h>
#include <hip/hip_bf16.h>
#include <cstdint>
#include <cstddef>

typedef __attribute__((ext_vector_type(4))) float f32x4;
typedef __attribute__((ext_vector_type(8))) __bf16 bf16x8;
typedef __attribute__((ext_vector_type(8))) unsigned short u16x8;
typedef __attribute__((ext_vector_type(4))) unsigned short u16x4;

#define B_ 256
#define T_ 512
#define I_ 128
#define H_ 1024
#define O_ 64
#define KTOT 1152          // H + I
#define RSTR 2304          // KTOT * 2 bytes, LDS row stride

__device__ inline unsigned short f2bf(float f){
  unsigned u = __builtin_bit_cast(unsigned, f);
  u += 0x7fffu + ((u >> 16) & 1u);          // RNE
  return (unsigned short)(u >> 16);
}

__global__ void cast_h0(const float* __restrict__ in, unsigned short* __restrict__ out){
  int i = (blockIdx.x * 256 + threadIdx.x) * 4;   // 256 blocks x 1024 elems
  f32x4 v = *reinterpret_cast<const f32x4*>(in + i);
  u16x4 o;
  #pragma unroll
  for (int k = 0; k < 4; ++k) o[k] = f2bf(v[k]);
  *reinterpret_cast<u16x4*>(out + i) = o;
}

__global__ void cast_V(const float* __restrict__ in, unsigned short* __restrict__ out){
  int i = (blockIdx.x * 256 + threadIdx.x) * 4;   // 64 blocks x 1024 elems = 65536
  f32x4 v = *reinterpret_cast<const f32x4*>(in + i);
  u16x4 o;
  #pragma unroll
  for (int k = 0; k < 4; ++k) o[k] = f2bf(v[k]);
  *reinterpret_cast<u16x4*>(out + i) = o;
}

// global->LDS direct, reading from the device coherence point (sc0|sc1)
__device__ inline void gload_lds16_llc(const unsigned short* src, void* dst){
  __builtin_amdgcn_global_load_lds(
      (const __attribute__((address_space(1))) unsigned int*)src,
      (__attribute__((address_space(3))) unsigned int*)dst, 16, 0, 17);
}

// Persistent cooperative fused RNN. grid=256 (8 batch-groups x 32 j-slices), block=256.
// Cross-block h/flags via relaxed agent atomics (LLC-coherent, fence-free).
// Flag layout: flags[bg*32 + ns]  (ns = j-slice index within group) — waiters poll
// exactly their own group's 32 writers. (Round-5 bug: published flags[blockIdx.x].)
// Y projection: rotating duty — block ns computes full Y[.,t-1,.] when (t-1)%32==ns,
// from the h_t already staged in its own LDS. No partial exchange.
// LDS: sU [32 x 1152 bf16] = [U|W] slice (swizzled, resident)      72 KB
//      sA [32 x 1152 bf16] = [h_t | x_t] stage (swizzled)          72 KB
//      sT [32 x 32 bf16]   = h tile transpose buffer                2 KB
__global__ __launch_bounds__(256, 1) void rnn_fused(
    const float* __restrict__ X, const float* __restrict__ U, const float* __restrict__ W,
    const float* __restrict__ Ubias, const unsigned short* __restrict__ Vbf,
    const float* __restrict__ Vbias,
    unsigned short* __restrict__ hbuf,   // 2 x B x H bf16
    float* __restrict__ Y,               // B x T x O
    float* __restrict__ hlast,           // B x H
    unsigned* __restrict__ flags){       // [8 groups][32 slices] step flags
  extern __shared__ char smem[];
  char* sUb = smem;                // 73728 B
  char* sAb = smem + 73728;        // 73728 B
  char* sTb = smem + 147456;       // 2048 B

  const int tid = threadIdx.x;
  const int wid = tid >> 6, lane = tid & 63;
  const int la = lane & 15, lg = lane >> 4;
  const int bg = blockIdx.x & 7, ns = blockIdx.x >> 3;
  const int b0 = bg * 32, j0 = ns * 32;

  // ---- preload [U|W] slice rows [j0,j0+32), fp32 -> bf16, swizzled ----
  for (int it = 0; it < 18; ++it){
    int c  = it * 256 + tid;          // 4608 chunks of 8 elems
    int r  = c / 144, cc = c % 144;
    const float* src = (cc < 128) ? (U + (size_t)(j0 + r) * H_ + cc * 8)
                                  : (W + (size_t)(j0 + r) * I_ + (cc - 128) * 8);
    f32x4 f0 = *reinterpret_cast<const f32x4*>(src);
    f32x4 f1 = *reinterpret_cast<const f32x4*>(src + 4);
    u16x8 o;
    #pragma unroll
    for (int k = 0; k < 4; ++k){ o[k] = f2bf(f0[k]); o[k + 4] = f2bf(f1[k]); }
    int boff = r * RSTR + ((cc * 16) ^ ((r & 7) << 4));
    *reinterpret_cast<u16x8*>(sUb + boff) = o;
  }

  // wave roles: recurrence out tile (b 16 x j 16); mw = batch half, nw = j half
  const int mw = wid & 1, nw = wid >> 1;
  const int rowA = (mw * 16 + la) * RSTR;
  const int rowB = (nw * 16 + la) * RSTR;
  const int sw   = (la & 7) << 4;
  const int cA   = (lg * 16) ^ sw;
  const int jme  = j0 + nw * 16 + la;
  const float ubv = Ubias[jme];
  // Y-projection: wave (mw,nw) covers b-half mw, o-tiles {2nw, 2nw+1} (nw in 0..1)
  const float vb0 = Vbias[(2 * nw)     * 16 + la];
  const float vb1 = Vbias[(2 * nw + 1) * 16 + la];

  __syncthreads();   // sU ready

  for (int t = 0; t <= T_; ++t){
    const bool turn = (t >= 1) && (((t - 1) & 31) == ns);
    if (t == T_ && !turn) break;            // only final-duty blocks run the tail

    const unsigned short* cur = hbuf + (size_t)(t & 1) * (B_ * H_);
    unsigned short*       nxt = hbuf + (size_t)((t + 1) & 1) * (B_ * H_);

    // ---- wait: all 32 writers of this bg have published h_t (flag >= t) ----
    if (tid < 32){
      while (__hip_atomic_load(&flags[bg * 32 + tid], __ATOMIC_RELAXED,
                               __HIP_MEMORY_SCOPE_AGENT) < (unsigned)t)
        __builtin_amdgcn_s_sleep(1);
    }
    __syncthreads();

    // ---- stage h (LLC -> LDS, linear dest, pre-swizzled source) ----
    #pragma unroll
    for (int it = 0; it < 16; ++it){
      int q    = it * 4 + wid;              // 64 chunks of 1KB
      int row  = q >> 1, half = q & 1;
      int swr  = (row & 7) << 4;
      int cb   = half * 1024 + lane * 16;
      int se   = (b0 + row) * H_ + (((cb ^ swr)) >> 1);
      gload_lds16_llc(cur + se, sAb + row * RSTR + half * 1024);
    }
    // ---- stage x_t (f32 -> bf16 -> LDS row tails, swizzled write) ----
    if (t < T_){
      int r = tid >> 3, sub = tid & 7;
      int swr = (r & 7) << 4;
      const float* xs = X + ((size_t)(b0 + r) * T_ + t) * I_ + sub * 16;
      f32x4 a0 = *reinterpret_cast<const f32x4*>(xs);
      f32x4 a1 = *reinterpret_cast<const f32x4*>(xs + 4);
      f32x4 a2 = *reinterpret_cast<const f32x4*>(xs + 8);
      f32x4 a3 = *reinterpret_cast<const f32x4*>(xs + 12);
      u16x8 o01, o23;
      #pragma unroll
      for (int k = 0; k < 4; ++k){
        o01[k] = f2bf(a0[k]); o01[k + 4] = f2bf(a1[k]);
        o23[k] = f2bf(a2[k]); o23[k + 4] = f2bf(a3[k]);
      }
      int cb = sub * 32;
      *reinterpret_cast<u16x8*>(sAb + r * RSTR + 2048 + (cb ^ swr))        = o01;
      *reinterpret_cast<u16x8*>(sAb + r * RSTR + 2048 + ((cb + 16) ^ swr)) = o23;
    }
    __syncthreads();   // staging complete

    if (t < T_){
      // ---- pre-activation: [h|x] . [U|W]^T, K = 1152 ----
      f32x4 acc0 = {0, 0, 0, 0}, acc1 = {0, 0, 0, 0};
      #pragma unroll
      for (int ks = 0; ks < 36; ++ks){
        bf16x8 a = *reinterpret_cast<const bf16x8*>(sAb + rowA + ((ks * 64) ^ cA));
        bf16x8 b = *reinterpret_cast<const bf16x8*>(sUb + rowB + ((ks * 64) ^ cA));
        if (ks & 1) acc1 = __builtin_amdgcn_mfma_f32_16x16x32_bf16(a, b, acc1, 0, 0, 0);
        else        acc0 = __builtin_amdgcn_mfma_f32_16x16x32_bf16(a, b, acc0, 0, 0, 0);
      }

      // ---- tanh epilogue -> sT; hlast on final step ----
      const int jl = nw * 16 + la;
      #pragma unroll
      for (int v = 0; v < 4; ++v){
        int b = mw * 16 + lg * 4 + v;
        float pre = acc0[v] + acc1[v] + ubv;
        float hv  = tanhf(pre);
        unsigned short hb = f2bf(hv);
        if (t == T_ - 1) hlast[(size_t)(b0 + b) * H_ + jme] = hv;
        *reinterpret_cast<unsigned short*>(sTb + b * 64 + ((jl * 2) ^ ((b & 3) << 4))) = hb;
      }
      __syncthreads();   // sT ready

      // ---- publish h_{t+1} (LLC atomic stores, 8B per thread from sT) ----
      {
        int br = tid >> 3, j0l = (tid & 7) * 4;
        u16x4 hv4 = *reinterpret_cast<const u16x4*>(sTb + br * 64 + ((j0l * 2) ^ ((br & 3) << 4)));
        uint64_t hp = __builtin_bit_cast(uint64_t, hv4);
        __hip_atomic_store((uint64_t*)(nxt + (size_t)(b0 + br) * H_ + j0 + j0l), hp,
                           __ATOMIC_RELAXED, __HIP_MEMORY_SCOPE_AGENT);
      }
      __syncthreads();   // all waves' LLC stores acked

      if (tid == 0)
        __hip_atomic_store(&flags[bg * 32 + ns], (unsigned)(t + 1),
                           __ATOMIC_RELAXED, __HIP_MEMORY_SCOPE_AGENT);
    }

    // ---- rotating duty: full V-projection for step t-1 from staged h_t ----
    if (turn){
      f32x4 y0a = {0,0,0,0}, y0b = {0,0,0,0};
      const unsigned short* v0p = Vbf + (size_t)((2 * nw)     * 16 + la) * H_ + lg * 8;
      const unsigned short* v1p = Vbf + (size_t)((2 * nw + 1) * 16 + la) * H_ + lg * 8;
      #pragma unroll 8
      for (int kt = 0; kt < 32; ++kt){
        bf16x8 a  = *reinterpret_cast<const bf16x8*>(sAb + rowA + ((kt * 64) ^ cA));
        bf16x8 f0 = *reinterpret_cast<const bf16x8*>(v0p + kt * 32);
        bf16x8 f1 = *reinterpret_cast<const bf16x8*>(v1p + kt * 32);
        y0a = __builtin_amdgcn_mfma_f32_16x16x32_bf16(a, f0, y0a, 0, 0, 0);
        y0b = __builtin_amdgcn_mfma_f32_16x16x32_bf16(a, f1, y0b, 0, 0, 0);
      }
      #pragma unroll
      for (int v = 0; v < 4; ++v){
        int b = mw * 16 + lg * 4 + v;
        float* yr = Y + ((size_t)(b0 + b) * T_ + (t - 1)) * O_;
        yr[(2 * nw)     * 16 + la] = y0a[v] + vb0;
        yr[(2 * nw + 1) * 16 + la] = y0b[v] + vb1;
      }
      __syncthreads();   // protect sA before next iteration's staging
    }
  }
}

extern "C" void kernel_launch(void* const* d_in, const int* in_sizes, int n_in,
                              void* d_out, int out_size, void* d_ws, size_t ws_size,
                              hipStream_t stream){
  const float* X  = (const float*)d_in[0];
  const float* h0 = (const float*)d_in[1];
  const float* W  = (const float*)d_in[2];
  const float* U  = (const float*)d_in[3];
  const float* Ub = (const float*)d_in[4];
  const float* V  = (const float*)d_in[5];
  const float* Vb = (const float*)d_in[6];
  float* Y     = (float*)d_out;
  float* hlast = Y + (size_t)B_ * T_ * O_;

  char* ws = (char*)d_ws;
  unsigned short* hbuf  = (unsigned short*)(ws);              // 1,048,576 B
  unsigned short* Vbf   = (unsigned short*)(ws + 1048576);    //   131,072 B
  unsigned*       flags = (unsigned*)(ws + 1179648);          //     1,024 B

  cast_h0<<<256, 256, 0, stream>>>(h0, hbuf);                 // hbuf[0] = bf16(h0)
  cast_V<<<64, 256, 0, stream>>>(V, Vbf);
  (void)hipMemsetAsync(flags, 0, 1024, stream);

  (void)hipFuncSetAttribute((const void*)rnn_fused,
                            hipFuncAttributeMaxDynamicSharedMemorySize, 149504);
  void* args[] = { (void*)&X, (void*)&U, (void*)&W, (void*)&Ub, (void*)&Vbf, (void*)&Vb,
                   (void*)&hbuf, (void*)&Y, (void*)&hlast, (void*)&flags };
  (void)hipLaunchCooperativeKernel((const void*)rnn_fused, dim3(256), dim3(256),
                                   args, 149504, stream);
}

// Round 7
// 2346.172 us; speedup vs baseline: 1.4958x; 1.4958x over previous
//
#include <hip/hip_runtime.h>
#include <hip/hip_bf16.h>
#include <cstdint>
#include <cstddef>

typedef __attribute__((ext_vector_type(4))) float f32x4;
typedef __attribute__((ext_vector_type(8))) __bf16 bf16x8;
typedef __attribute__((ext_vector_type(8))) unsigned short u16x8;
typedef __attribute__((ext_vector_type(4))) unsigned short u16x4;

#define B_ 256
#define T_ 512
#define I_ 128
#define H_ 1024
#define O_ 64
#define KTOT 1152          // H + I
#define RSTR 2304          // KTOT * 2 bytes, LDS row stride

__device__ inline unsigned short f2bf(float f){
  unsigned u = __builtin_bit_cast(unsigned, f);
  u += 0x7fffu + ((u >> 16) & 1u);          // RNE
  return (unsigned short)(u >> 16);
}

// tanh(x) = 1 - 2/(exp2(x*2*log2e)+1); HW exp2/rcp, saturates correctly.
__device__ inline float fast_tanh(float x){
  float e = __builtin_amdgcn_exp2f(x * 2.885390081777927f);   // e^(2x)
  return 1.0f - 2.0f * __builtin_amdgcn_rcpf(e + 1.0f);
}

__global__ void cast_h0(const float* __restrict__ in, unsigned short* __restrict__ out){
  int i = (blockIdx.x * 256 + threadIdx.x) * 4;
  f32x4 v = *reinterpret_cast<const f32x4*>(in + i);
  u16x4 o;
  #pragma unroll
  for (int k = 0; k < 4; ++k) o[k] = f2bf(v[k]);
  *reinterpret_cast<u16x4*>(out + i) = o;
}

__global__ void cast_V(const float* __restrict__ in, unsigned short* __restrict__ out){
  int i = (blockIdx.x * 256 + threadIdx.x) * 4;
  f32x4 v = *reinterpret_cast<const f32x4*>(in + i);
  u16x4 o;
  #pragma unroll
  for (int k = 0; k < 4; ++k) o[k] = f2bf(v[k]);
  *reinterpret_cast<u16x4*>(out + i) = o;
}

// global->LDS direct, reading from the device coherence point (sc0|sc1)
__device__ inline void gload_lds16_llc(const unsigned short* src, void* dst){
  __builtin_amdgcn_global_load_lds(
      (const __attribute__((address_space(1))) unsigned int*)src,
      (__attribute__((address_space(3))) unsigned int*)dst, 16, 0, 17);
}

// Persistent cooperative fused RNN. grid=256 (8 batch-groups x 32 j-slices), block=256.
// Cross-block h/flags via relaxed agent atomics (LLC-coherent, fence-free).
// flags[bg*32+ns]; waiters poll exactly their group's 32 writers.
// U/W fragments live in REGISTERS (loaded once via LDS); MFMA loop reads only A from LDS.
// Y projection: rotating duty split across TWO blocks per step (16 rows each).
__global__ __launch_bounds__(256, 1) void rnn_fused(
    const float* __restrict__ X, const float* __restrict__ U, const float* __restrict__ W,
    const float* __restrict__ Ubias, const unsigned short* __restrict__ Vbf,
    const float* __restrict__ Vbias,
    unsigned short* __restrict__ hbuf,   // 2 x B x H bf16
    float* __restrict__ Y,               // B x T x O
    float* __restrict__ hlast,           // B x H
    unsigned* __restrict__ flags){       // [8 groups][32 slices] step flags
  extern __shared__ char smem[];
  char* sUb = smem;                // 73728 B (preload scratch for U-frag hoist)
  char* sAb = smem + 73728;        // 73728 B
  char* sTb = smem + 147456;       // 2048 B

  const int tid = threadIdx.x;
  const int wid = tid >> 6, lane = tid & 63;
  const int la = lane & 15, lg = lane >> 4;
  const int bg = blockIdx.x & 7, ns = blockIdx.x >> 3;
  const int b0 = bg * 32, j0 = ns * 32;

  // ---- preload [U|W] slice rows [j0,j0+32), fp32 -> bf16, swizzled into LDS ----
  for (int it = 0; it < 18; ++it){
    int c  = it * 256 + tid;
    int r  = c / 144, cc = c % 144;
    const float* src = (cc < 128) ? (U + (size_t)(j0 + r) * H_ + cc * 8)
                                  : (W + (size_t)(j0 + r) * I_ + (cc - 128) * 8);
    f32x4 f0 = *reinterpret_cast<const f32x4*>(src);
    f32x4 f1 = *reinterpret_cast<const f32x4*>(src + 4);
    u16x8 o;
    #pragma unroll
    for (int k = 0; k < 4; ++k){ o[k] = f2bf(f0[k]); o[k + 4] = f2bf(f1[k]); }
    int boff = r * RSTR + ((cc * 16) ^ ((r & 7) << 4));
    *reinterpret_cast<u16x8*>(sUb + boff) = o;
  }

  // wave roles: recurrence out tile (b 16 x j 16); mw = batch half, nw = j half
  const int mw = wid & 1, nw = wid >> 1;
  const int rowA = (mw * 16 + la) * RSTR;
  const int rowB = (nw * 16 + la) * RSTR;
  const int sw   = (la & 7) << 4;
  const int cA   = (lg * 16) ^ sw;
  const int jme  = j0 + nw * 16 + la;
  const float ubv = Ubias[jme];

  __syncthreads();   // sU ready

  // ---- hoist U/W fragments to registers (constant across all 512 steps) ----
  bf16x8 ufr[36];
  #pragma unroll
  for (int ks = 0; ks < 36; ++ks)
    ufr[ks] = *reinterpret_cast<const bf16x8*>(sUb + rowB + ((ks * 64) ^ cA));

  // ---- x prefetch registers (16 floats/thread), preload t=0 ----
  const int xr = tid >> 3, xsub = tid & 7;
  f32x4 xp0, xp1, xp2, xp3;
  {
    const float* xs = X + ((size_t)(b0 + xr) * T_ + 0) * I_ + xsub * 16;
    xp0 = *reinterpret_cast<const f32x4*>(xs);
    xp1 = *reinterpret_cast<const f32x4*>(xs + 4);
    xp2 = *reinterpret_cast<const f32x4*>(xs + 8);
    xp3 = *reinterpret_cast<const f32x4*>(xs + 12);
  }

  for (int t = 0; t <= T_; ++t){
    const int dns = (t - 1) & 31;
    const bool turnA = (t >= 1) && (dns == ns);          // duty rows 0..15
    const bool turnB = (t >= 1) && ((dns ^ 16) == ns);   // duty rows 16..31
    if (t == T_ && !(turnA || turnB)) break;

    const unsigned short* cur = hbuf + (size_t)(t & 1) * (B_ * H_);
    unsigned short*       nxt = hbuf + (size_t)((t + 1) & 1) * (B_ * H_);

    // ---- wait: all 32 writers of this bg have published h_t ----
    if (tid < 32){
      while (__hip_atomic_load(&flags[bg * 32 + tid], __ATOMIC_RELAXED,
                               __HIP_MEMORY_SCOPE_AGENT) < (unsigned)t)
        __builtin_amdgcn_s_sleep(1);
    }
    __syncthreads();

    // ---- stage h (LLC -> LDS, linear dest, pre-swizzled source) ----
    #pragma unroll
    for (int it = 0; it < 16; ++it){
      int q    = it * 4 + wid;
      int row  = q >> 1, half = q & 1;
      int swr  = (row & 7) << 4;
      int cb   = half * 1024 + lane * 16;
      int se   = (b0 + row) * H_ + (((cb ^ swr)) >> 1);
      gload_lds16_llc(cur + se, sAb + row * RSTR + half * 1024);
    }
    // ---- write x_t from prefetch regs (no global load in this window) ----
    if (t < T_){
      int swr = (xr & 7) << 4;
      u16x8 o01, o23;
      #pragma unroll
      for (int k = 0; k < 4; ++k){
        o01[k] = f2bf(xp0[k]); o01[k + 4] = f2bf(xp1[k]);
        o23[k] = f2bf(xp2[k]); o23[k + 4] = f2bf(xp3[k]);
      }
      int cb = xsub * 32;
      *reinterpret_cast<u16x8*>(sAb + xr * RSTR + 2048 + (cb ^ swr))        = o01;
      *reinterpret_cast<u16x8*>(sAb + xr * RSTR + 2048 + ((cb + 16) ^ swr)) = o23;
    }
    __syncthreads();   // staging complete

    // ---- issue x(t+1) prefetch (drains during epilogue sync, off critical path) ----
    if (t < T_ - 1){
      const float* xs = X + ((size_t)(b0 + xr) * T_ + (t + 1)) * I_ + xsub * 16;
      xp0 = *reinterpret_cast<const f32x4*>(xs);
      xp1 = *reinterpret_cast<const f32x4*>(xs + 4);
      xp2 = *reinterpret_cast<const f32x4*>(xs + 8);
      xp3 = *reinterpret_cast<const f32x4*>(xs + 12);
    }

    if (t < T_){
      // ---- pre-activation: [h|x] . [U|W]^T, K = 1152; B-operand from registers ----
      f32x4 acc0 = {0, 0, 0, 0}, acc1 = {0, 0, 0, 0};
      #pragma unroll
      for (int ks = 0; ks < 36; ++ks){
        bf16x8 a = *reinterpret_cast<const bf16x8*>(sAb + rowA + ((ks * 64) ^ cA));
        if (ks & 1) acc1 = __builtin_amdgcn_mfma_f32_16x16x32_bf16(a, ufr[ks], acc1, 0, 0, 0);
        else        acc0 = __builtin_amdgcn_mfma_f32_16x16x32_bf16(a, ufr[ks], acc0, 0, 0, 0);
      }

      // ---- tanh epilogue -> sT; hlast on final step ----
      const int jl = nw * 16 + la;
      #pragma unroll
      for (int v = 0; v < 4; ++v){
        int b = mw * 16 + lg * 4 + v;
        float pre = acc0[v] + acc1[v] + ubv;
        float hv  = fast_tanh(pre);
        unsigned short hb = f2bf(hv);
        if (t == T_ - 1) hlast[(size_t)(b0 + b) * H_ + jme] = hv;
        *reinterpret_cast<unsigned short*>(sTb + b * 64 + ((jl * 2) ^ ((b & 3) << 4))) = hb;
      }
      __syncthreads();   // sT ready

      // ---- publish h_{t+1} (LLC atomic stores, 8B per thread from sT) ----
      {
        int br = tid >> 3, j0l = (tid & 7) * 4;
        u16x4 hv4 = *reinterpret_cast<const u16x4*>(sTb + br * 64 + ((j0l * 2) ^ ((br & 3) << 4)));
        uint64_t hp = __builtin_bit_cast(uint64_t, hv4);
        __hip_atomic_store((uint64_t*)(nxt + (size_t)(b0 + br) * H_ + j0 + j0l), hp,
                           __ATOMIC_RELAXED, __HIP_MEMORY_SCOPE_AGENT);
      }
      __syncthreads();   // all waves' LLC stores acked

      if (tid == 0)
        __hip_atomic_store(&flags[bg * 32 + ns], (unsigned)(t + 1),
                           __ATOMIC_RELAXED, __HIP_MEMORY_SCOPE_AGENT);
    }

    // ---- rotating duty (split): Y[.,t-1] rows rb0..rb0+15, all 64 o ----
    if (turnA || turnB){
      const int rb0 = turnA ? 0 : 16;
      // wave wid covers o-tile [wid*16, wid*16+16); A rows rb0+la (swizzle uses la&7, valid for rb0 in {0,16})
      const int orow = wid * 16 + la;
      const unsigned short* vp = Vbf + (size_t)orow * H_ + lg * 8;
      f32x4 y = {0, 0, 0, 0};
      #pragma unroll 8
      for (int kt = 0; kt < 32; ++kt){
        bf16x8 a = *reinterpret_cast<const bf16x8*>(sAb + (rb0 + la) * RSTR + ((kt * 64) ^ cA));
        bf16x8 f = *reinterpret_cast<const bf16x8*>(vp + kt * 32);
        y = __builtin_amdgcn_mfma_f32_16x16x32_bf16(a, f, y, 0, 0, 0);
      }
      const float vb = Vbias[orow];
      #pragma unroll
      for (int v = 0; v < 4; ++v){
        int b = rb0 + lg * 4 + v;
        Y[((size_t)(b0 + b) * T_ + (t - 1)) * O_ + orow] = y[v] + vb;
      }
      __syncthreads();   // protect sA before next iteration's staging
    }
  }
}

extern "C" void kernel_launch(void* const* d_in, const int* in_sizes, int n_in,
                              void* d_out, int out_size, void* d_ws, size_t ws_size,
                              hipStream_t stream){
  const float* X  = (const float*)d_in[0];
  const float* h0 = (const float*)d_in[1];
  const float* W  = (const float*)d_in[2];
  const float* U  = (const float*)d_in[3];
  const float* Ub = (const float*)d_in[4];
  const float* V  = (const float*)d_in[5];
  const float* Vb = (const float*)d_in[6];
  float* Y     = (float*)d_out;
  float* hlast = Y + (size_t)B_ * T_ * O_;

  char* ws = (char*)d_ws;
  unsigned short* hbuf  = (unsigned short*)(ws);              // 1,048,576 B
  unsigned short* Vbf   = (unsigned short*)(ws + 1048576);    //   131,072 B
  unsigned*       flags = (unsigned*)(ws + 1179648);          //     1,024 B

  cast_h0<<<256, 256, 0, stream>>>(h0, hbuf);                 // hbuf[0] = bf16(h0)
  cast_V<<<64, 256, 0, stream>>>(V, Vbf);
  (void)hipMemsetAsync(flags, 0, 1024, stream);

  (void)hipFuncSetAttribute((const void*)rnn_fused,
                            hipFuncAttributeMaxDynamicSharedMemorySize, 149504);
  void* args[] = { (void*)&X, (void*)&U, (void*)&W, (void*)&Ub, (void*)&Vbf, (void*)&Vb,
                   (void*)&hbuf, (void*)&Y, (void*)&hlast, (void*)&flags };
  (void)hipLaunchCooperativeKernel((const void*)rnn_fused, dim3(256), dim3(256),
                                   args, 149504, stream);
}